// Round 4
// baseline (8472.201 us; speedup 1.0000x reference)
//
#include <hip/hip_runtime.h>
#include <hip/hip_bf16.h>
#include <stdint.h>

#define B_   64
#define T_   1024
#define D_   300
#define H_   512
#define G4H  2048
#define KP   320   // K padded to multiple of 32 for the x-proj GEMM

typedef __attribute__((ext_vector_type(8))) short short8;   // 8 x bf16 (4 VGPRs)
typedef __attribute__((ext_vector_type(4))) float f32x4;
typedef unsigned long long ull;

__device__ __forceinline__ unsigned short f2bf(float v) {
    __hip_bfloat16 h = __float2bfloat16(v);
    return *reinterpret_cast<unsigned short*>(&h);
}
__device__ __forceinline__ float bf2f(unsigned u) {      // low 16 bits = bf16
    return __uint_as_float(u << 16);
}
__device__ __forceinline__ float sigm(float x) { return 1.f / (1.f + __expf(-x)); }
__device__ __forceinline__ float tanhfast(float x) {
    float e = __expf(2.f * x);            // inf-safe: x>>0 -> 1, x<<0 -> -1
    return 1.f - 2.f / (e + 1.f);
}

#define ASYNC16(g, l)                                                        \
    __builtin_amdgcn_global_load_lds(                                        \
        (const __attribute__((address_space(1))) void*)(g),                  \
        (__attribute__((address_space(3))) void*)(l), 16, 0, 0)

// ---------------------------------------------------------------------------
// Kernel 1: essays fp32 [65536][300] -> bf16 [65536][320] (zero-padded K)
// ---------------------------------------------------------------------------
__global__ void cvt_essays(const float* __restrict__ es, unsigned short* __restrict__ Ab) {
    unsigned i = blockIdx.x * 256u + threadIdx.x;       // exactly 65536*320 threads
    unsigned row = i / KP;
    unsigned col = i - row * KP;
    float v = (col < D_) ? es[(size_t)row * D_ + col] : 0.f;
    Ab[i] = f2bf(v);
}

// ---------------------------------------------------------------------------
// Kernel 2: Wx transpose+pad -> bf16 WxT[2048][320]
// ---------------------------------------------------------------------------
__global__ void cvt_misc(const float* __restrict__ Wl, unsigned short* __restrict__ Bt) {
    unsigned i = blockIdx.x * 256u + threadIdx.x;       // exactly 2048*320 threads
    unsigned n = i / KP, k = i - n * KP;
    float v = (k < D_) ? Wl[(size_t)k * G4H + n] : 0.f;   // Wx rows 0..299
    Bt[i] = f2bf(v);
}

// ---------------------------------------------------------------------------
// Kernel 2b: Wh transpose -> bf16 WhTg[2048][512] (coalesced block staging)
// ---------------------------------------------------------------------------
__global__ void cvt_wh(const float* __restrict__ Wl, unsigned short* __restrict__ WhTg) {
    unsigned i = blockIdx.x * 256u + threadIdx.x;       // 2048*512 threads
    unsigned gc = i & 2047u, k = i >> 11;
    WhTg[(size_t)gc * 512 + k] = f2bf(Wl[(size_t)(300 + k) * G4H + gc]);
}

// ---------------------------------------------------------------------------
// Kernel 3: x_proj GEMM  C[65536][2048] = A[65536][320] @ WxT^T + b_lstm (bf16 out)
// ---------------------------------------------------------------------------
__global__ __launch_bounds__(256) void gemm_xp(
    const unsigned short* __restrict__ Ab,   // [65536][320] bf16
    const unsigned short* __restrict__ Bt,   // [2048][320]  bf16 (WxT)
    const float* __restrict__ bias,          // [2048]
    unsigned short* __restrict__ Cb)         // [65536][2048] bf16
{
    __shared__ __align__(16) unsigned short Al[128 * 32];
    __shared__ __align__(16) unsigned short Bl[128 * 32];
    const int tid = threadIdx.x;
    const int w = tid >> 6, lane = tid & 63;
    const int ln = lane & 15, q = lane >> 4;
    const int bx = blockIdx.x;
    const int m0 = (bx >> 4) * 128;          // consecutive blocks share the A tile
    const int n0 = (bx & 15) * 128;
    const int wr = w >> 1, wc = w & 1;

    f32x4 acc[4][4];
#pragma unroll
    for (int i = 0; i < 4; i++)
#pragma unroll
        for (int j = 0; j < 4; j++) acc[i][j] = (f32x4){0.f, 0.f, 0.f, 0.f};

    for (int k0 = 0; k0 < KP; k0 += 32) {
#pragma unroll
        for (int it = 0; it < 2; ++it) {
            int s = it * 4 + w;              // wave-uniform segment id
            int c = s * 64 + lane;           // 16B chunk id, 0..511
            int r = c >> 2;                  // tile row 0..127
            int ko = (c & 3) * 8;            // k offset in elements
            ASYNC16(Ab + (size_t)(m0 + r) * KP + k0 + ko, &Al[s * 512]);
            ASYNC16(Bt + (size_t)(n0 + r) * KP + k0 + ko, &Bl[s * 512]);
        }
        __syncthreads();
        short8 af[4], bf[4];
#pragma unroll
        for (int mt = 0; mt < 4; ++mt)
            af[mt] = *(const short8*)&Al[(wr * 64 + mt * 16 + ln) * 32 + q * 8];
#pragma unroll
        for (int nt = 0; nt < 4; ++nt)
            bf[nt] = *(const short8*)&Bl[(wc * 64 + nt * 16 + ln) * 32 + q * 8];
#pragma unroll
        for (int mt = 0; mt < 4; ++mt)
#pragma unroll
            for (int nt = 0; nt < 4; ++nt)
                acc[mt][nt] = __builtin_amdgcn_mfma_f32_16x16x32_bf16(af[mt], bf[nt], acc[mt][nt], 0, 0, 0);
        __syncthreads();
    }
#pragma unroll
    for (int mt = 0; mt < 4; ++mt) {
#pragma unroll
        for (int nt = 0; nt < 4; ++nt) {
            int col = n0 + wc * 64 + nt * 16 + ln;
            float bb = bias[col];
#pragma unroll
            for (int r = 0; r < 4; ++r) {
                int row = m0 + wr * 64 + mt * 16 + q * 4 + r;   // C/D: col=lane&15, row=quad*4+reg
                Cb[(size_t)row * G4H + col] = f2bf(acc[mt][nt][r] + bb);
            }
        }
    }
}

// ---------------------------------------------------------------------------
// Kernel 4: persistent LSTM recurrence — FLAGLESS data-as-flag protocol.
// 4 groups x 32 j-slices = 128 blocks, 1/CU. h stored fp32 encoded
// e = sign * (h + 4), sign = ((step)>>1)&1. |h|<1 => |e| in (3,5) =>
// (bits>>30) == 1 (positive phase) or 3 (negative phase). Stale data (2
// steps old, same buffer) has opposite phase; 0xAA poison gives 2. Consumers
// poll the data dwords themselves (relaxed agent loads) — no fences/flags.
// Safety: a writer of h(t+2) has validated ALL of h(t+1), which implies every
// block in the group finished reading h(t) — so buffer[t&1] reuse is safe.
// ---------------------------------------------------------------------------
__global__ __launch_bounds__(256, 1) void lstm_rec(
    const unsigned short* __restrict__ WhTg, // [2048][512] bf16 (pre-transposed Wh)
    const unsigned short* __restrict__ xp,   // [65536][2048] bf16 (x_proj + bias)
    unsigned* __restrict__ hfp,              // [2][64][512] fp32-encoded h
    float* __restrict__ hmean)               // [64][512] fp32
{
    __shared__ __align__(16) unsigned short WhT[64 * 520];   // [col][k], pad 520
    __shared__ __align__(16) unsigned short hl[16 * 520];    // [b][k], pad 520
    __shared__ float gbuf[4][16][17];                        // [gate][b][j], pad 17

    const int tid = threadIdx.x;
    const int bid = blockIdx.x;
    const int g     = bid >> 5;        // batch group 0..3
    const int slice = bid & 31;        // j-slice 0..31
    const int j0    = slice * 16;
    const int bg    = g * 16;
    const int wv = tid >> 6, lane = tid & 63, ln = lane & 15, q = lane >> 4;

    // one-time: stage this block's 64 Wh columns (gate*16+j) from WhTg, coalesced
    for (int ch = tid; ch < 64 * 64; ch += 256) {            // 16B chunks
        int c = ch >> 6, off = (ch & 63) * 8;
        int gc = (c >> 4) * 512 + j0 + (c & 15);
        *(uint4*)&WhT[c * 520 + off] = *(const uint4*)&WhTg[(size_t)gc * 512 + off];
    }

    const int b  = tid >> 4;           // local batch row 0..15 (also staging row)
    const int j  = tid & 15;           // local j
    const int kseg = j * 32;           // staging: 32 dwords of row b
    const int rowoff = (bg + b) * 512;

    // h(0) = 0: zero this thread's hl segment
    {
        uint4 z = {0u, 0u, 0u, 0u};
        uint4* d = (uint4*)&hl[b * 520 + kseg];
        d[0] = z; d[1] = z; d[2] = z; d[3] = z;
    }

    float c_st = 0.f, hsum = 0.f;
    const unsigned short* xrow = xp + (size_t)(bg + b) * T_ * G4H + j0 + j;
    unsigned short xc0 = xrow[0], xc1 = xrow[512], xc2 = xrow[1024], xc3 = xrow[1536];
    unsigned short xn0 = xc0, xn1 = xc1, xn2 = xc2, xn3 = xc3;

    for (int t = 0; t < T_; ++t) {
        // issue xp(t+1) prefetch FIRST: its latency hides under the poll below
        if (t + 1 < T_) {
            const unsigned short* xr = xrow + (size_t)(t + 1) * G4H;
            xn0 = xr[0]; xn1 = xr[512]; xn2 = xr[1024]; xn3 = xr[1536];
        }
        if (t > 0) {
            // poll h(t): each dword self-validates by phase bits
            const unsigned* src = hfp + (size_t)(t & 1) * 32768 + rowoff + kseg;
            const unsigned want = ((t >> 1) & 1) ? 3u : 1u;
            unsigned v[32];
#pragma unroll
            for (int i = 0; i < 32; ++i)
                v[i] = __hip_atomic_load(src + i, __ATOMIC_RELAXED, __HIP_MEMORY_SCOPE_AGENT);
            while (true) {
                unsigned bad = 0u;
#pragma unroll
                for (int i = 0; i < 32; ++i)
                    bad |= (((v[i] >> 30) & 3u) != want) ? (1u << i) : 0u;
                if (!bad) break;
#pragma unroll
                for (int i = 0; i < 32; ++i)
                    if (bad & (1u << i))
                        v[i] = __hip_atomic_load(src + i, __ATOMIC_RELAXED, __HIP_MEMORY_SCOPE_AGENT);
            }
            // decode |e|-4 -> bf16, pack pairs, write 64B to LDS
            unsigned u[16];
#pragma unroll
            for (int i = 0; i < 16; ++i) {
                unsigned b0 = f2bf(__uint_as_float(v[2 * i]     & 0x7fffffffu) - 4.0f);
                unsigned b1 = f2bf(__uint_as_float(v[2 * i + 1] & 0x7fffffffu) - 4.0f);
                u[i] = b0 | (b1 << 16);
            }
            uint4* d = (uint4*)&hl[b * 520 + kseg];
            d[0] = *(uint4*)&u[0];  d[1] = *(uint4*)&u[4];
            d[2] = *(uint4*)&u[8];  d[3] = *(uint4*)&u[12];
        }
        __syncthreads();                                     // sync1

        // wave wv computes gate wv: 16(batch) x 16(j), K=512
        f32x4 acc = (f32x4){0.f, 0.f, 0.f, 0.f};
#pragma unroll
        for (int kk = 0; kk < 16; ++kk) {
            short8 av = *(const short8*)&hl[ln * 520 + kk * 32 + q * 8];
            short8 bv = *(const short8*)&WhT[(wv * 16 + ln) * 520 + kk * 32 + q * 8];
            acc = __builtin_amdgcn_mfma_f32_16x16x32_bf16(av, bv, acc, 0, 0, 0);
        }
#pragma unroll
        for (int r = 0; r < 4; ++r)
            gbuf[wv][q * 4 + r][ln] = acc[r];                // C/D: col=lane&15, row=quad*4+reg
        __syncthreads();                                     // sync2

        // elementwise: thread (b, j)
        float ai  = gbuf[0][b][j] + bf2f((unsigned)xc0);
        float aj  = gbuf[1][b][j] + bf2f((unsigned)xc1);
        float af_ = gbuf[2][b][j] + bf2f((unsigned)xc2);
        float ao  = gbuf[3][b][j] + bf2f((unsigned)xc3);
        float si = sigm(ai), tj = tanhfast(aj);
        float sf = sigm(af_ + 1.0f), so = sigm(ao);
        c_st = c_st * sf + si * tj;
        float h = tanhfast(c_st) * so;
        hsum += h;
        xc0 = xn0; xc1 = xn1; xc2 = xn2; xc3 = xn3;

        // fire-and-forget encoded store of h(t+1); no drain, no flag
        float e = h + 4.0f;
        if (((t + 1) >> 1) & 1) e = -e;
        __hip_atomic_store(hfp + (size_t)((t + 1) & 1) * 32768 + rowoff + j0 + j,
                           __float_as_uint(e), __ATOMIC_RELAXED, __HIP_MEMORY_SCOPE_AGENT);
    }
    hmean[(size_t)rowoff + j0 + j] = hsum * (1.f / 1024.f);
}

// ---------------------------------------------------------------------------
// Kernel 5: preds = sigmoid(hmean @ W_dense + b_dense), one wave per batch row
// ---------------------------------------------------------------------------
__global__ void dense_out(const float* __restrict__ hmean, const float* __restrict__ Wd,
                          const float* __restrict__ bd, float* __restrict__ out) {
    int bb = blockIdx.x;
    int lane = threadIdx.x;
    float p = 0.f;
    for (int e = lane; e < H_; e += 64) p += hmean[(size_t)bb * H_ + e] * Wd[e];
#pragma unroll
    for (int off = 32; off; off >>= 1) p += __shfl_down(p, off);
    if (lane == 0) out[bb] = 1.f / (1.f + __expf(-(p + bd[0])));
}

// ---------------------------------------------------------------------------
extern "C" void kernel_launch(void* const* d_in, const int* in_sizes, int n_in,
                              void* d_out, int out_size, void* d_ws, size_t ws_size,
                              hipStream_t stream) {
    const float* essays  = (const float*)d_in[0];
    const float* W_lstm  = (const float*)d_in[1];
    const float* b_lstm  = (const float*)d_in[2];
    const float* W_dense = (const float*)d_in[3];
    const float* b_dense = (const float*)d_in[4];
    float* out = (float*)d_out;

    char* ws = (char*)d_ws;
    unsigned short* xp   = (unsigned short*)(ws);                   // 256 MB
    unsigned short* Ab   = (unsigned short*)(ws + 268435456ull);    // 40 MB (dead after gemm_xp)
    unsigned short* Bt   = (unsigned short*)(ws + 310378496ull);    // 1.25 MB
    unsigned short* WhTg = (unsigned short*)(ws + 311689216ull);    // 2 MB
    // hfp/hm overlap the Ab region (Ab is dead once gemm_xp completes;
    // stream ordering guarantees gemm_xp < lstm_rec)
    unsigned*       hfp  = (unsigned*)(ws + 268435456ull);          // 256 KB
    float*          hm   = (float*)(ws + 268435456ull + 262144ull); // 128 KB

    hipLaunchKernelGGL(cvt_essays, dim3(81920), dim3(256), 0, stream, essays, Ab);
    hipLaunchKernelGGL(cvt_misc,   dim3(2560),  dim3(256), 0, stream, W_lstm, Bt);
    hipLaunchKernelGGL(cvt_wh,     dim3(4096),  dim3(256), 0, stream, W_lstm, WhTg);
    hipLaunchKernelGGL(gemm_xp,    dim3(8192),  dim3(256), 0, stream, Ab, Bt, b_lstm, xp);
    hipLaunchKernelGGL(lstm_rec,   dim3(128),   dim3(256), 0, stream, WhTg, xp, hfp, hm);
    hipLaunchKernelGGL(dense_out,  dim3(64),    dim3(64),  0, stream, hm, W_dense, b_dense, out);
}

// Round 5
// 3620.135 us; speedup vs baseline: 2.3403x; 2.3403x over previous
//
#include <hip/hip_runtime.h>
#include <hip/hip_bf16.h>
#include <stdint.h>

#define B_   64
#define T_   1024
#define D_   300
#define H_   512
#define G4H  2048
#define KP   320   // K padded to multiple of 32 for the x-proj GEMM

typedef __attribute__((ext_vector_type(8))) short short8;   // 8 x bf16 (4 VGPRs)
typedef __attribute__((ext_vector_type(4))) float f32x4;
typedef unsigned long long ull;

__device__ __forceinline__ unsigned short f2bf(float v) {
    __hip_bfloat16 h = __float2bfloat16(v);
    return *reinterpret_cast<unsigned short*>(&h);
}
__device__ __forceinline__ float bf2f(unsigned u) {      // low 16 bits = bf16
    return __uint_as_float(u << 16);
}
__device__ __forceinline__ float sigm(float x) { return 1.f / (1.f + __expf(-x)); }
__device__ __forceinline__ float tanhfast(float x) {
    float e = __expf(2.f * x);            // inf-safe: x>>0 -> 1, x<<0 -> -1
    return 1.f - 2.f / (e + 1.f);
}

#define ASYNC16(g, l)                                                        \
    __builtin_amdgcn_global_load_lds(                                        \
        (const __attribute__((address_space(1))) void*)(g),                  \
        (__attribute__((address_space(3))) void*)(l), 16, 0, 0)

// ---------------------------------------------------------------------------
// Kernel 1: essays fp32 [65536][300] -> bf16 [65536][320] (zero-padded K)
// ---------------------------------------------------------------------------
__global__ void cvt_essays(const float* __restrict__ es, unsigned short* __restrict__ Ab) {
    unsigned i = blockIdx.x * 256u + threadIdx.x;       // exactly 65536*320 threads
    unsigned row = i / KP;
    unsigned col = i - row * KP;
    float v = (col < D_) ? es[(size_t)row * D_ + col] : 0.f;
    Ab[i] = f2bf(v);
}

// ---------------------------------------------------------------------------
// Kernel 2: Wx transpose+pad -> bf16 WxT[2048][320]
// ---------------------------------------------------------------------------
__global__ void cvt_misc(const float* __restrict__ Wl, unsigned short* __restrict__ Bt) {
    unsigned i = blockIdx.x * 256u + threadIdx.x;       // exactly 2048*320 threads
    unsigned n = i / KP, k = i - n * KP;
    float v = (k < D_) ? Wl[(size_t)k * G4H + n] : 0.f;   // Wx rows 0..299
    Bt[i] = f2bf(v);
}

// ---------------------------------------------------------------------------
// Kernel 2b: Wh transpose -> bf16 WhTg[2048][512] (coalesced block staging)
// ---------------------------------------------------------------------------
__global__ void cvt_wh(const float* __restrict__ Wl, unsigned short* __restrict__ WhTg) {
    unsigned i = blockIdx.x * 256u + threadIdx.x;       // 2048*512 threads
    unsigned gc = i & 2047u, k = i >> 11;
    WhTg[(size_t)gc * 512 + k] = f2bf(Wl[(size_t)(300 + k) * G4H + gc]);
}

// ---------------------------------------------------------------------------
// Kernel 3: x_proj GEMM -> xpr in recurrence layout:
//   xpr[((t*4+g)*32+slice)*1024 + b*64 + gate*16 + jj]   (bf16, bias added)
// where row = (g*16+b)*1024 + t, col = gate*512 + slice*16 + jj.
// Each lstm block-step then reads one contiguous 2 KB region.
// ---------------------------------------------------------------------------
__global__ __launch_bounds__(256) void gemm_xp(
    const unsigned short* __restrict__ Ab,   // [65536][320] bf16
    const unsigned short* __restrict__ Bt,   // [2048][320]  bf16 (WxT)
    const float* __restrict__ bias,          // [2048]
    unsigned short* __restrict__ xpr)        // [65536*2048] bf16, permuted
{
    __shared__ __align__(16) unsigned short Al[128 * 32];
    __shared__ __align__(16) unsigned short Bl[128 * 32];
    const int tid = threadIdx.x;
    const int w = tid >> 6, lane = tid & 63;
    const int ln = lane & 15, q = lane >> 4;
    const int bx = blockIdx.x;
    const int m0 = (bx >> 4) * 128;          // consecutive blocks share the A tile
    const int n0 = (bx & 15) * 128;
    const int wr = w >> 1, wc = w & 1;

    f32x4 acc[4][4];
#pragma unroll
    for (int i = 0; i < 4; i++)
#pragma unroll
        for (int j = 0; j < 4; j++) acc[i][j] = (f32x4){0.f, 0.f, 0.f, 0.f};

    for (int k0 = 0; k0 < KP; k0 += 32) {
#pragma unroll
        for (int it = 0; it < 2; ++it) {
            int s = it * 4 + w;              // wave-uniform segment id
            int c = s * 64 + lane;           // 16B chunk id, 0..511
            int r = c >> 2;                  // tile row 0..127
            int ko = (c & 3) * 8;            // k offset in elements
            ASYNC16(Ab + (size_t)(m0 + r) * KP + k0 + ko, &Al[s * 512]);
            ASYNC16(Bt + (size_t)(n0 + r) * KP + k0 + ko, &Bl[s * 512]);
        }
        __syncthreads();
        short8 af[4], bf[4];
#pragma unroll
        for (int mt = 0; mt < 4; ++mt)
            af[mt] = *(const short8*)&Al[(wr * 64 + mt * 16 + ln) * 32 + q * 8];
#pragma unroll
        for (int nt = 0; nt < 4; ++nt)
            bf[nt] = *(const short8*)&Bl[(wc * 64 + nt * 16 + ln) * 32 + q * 8];
#pragma unroll
        for (int mt = 0; mt < 4; ++mt)
#pragma unroll
            for (int nt = 0; nt < 4; ++nt)
                acc[mt][nt] = __builtin_amdgcn_mfma_f32_16x16x32_bf16(af[mt], bf[nt], acc[mt][nt], 0, 0, 0);
        __syncthreads();
    }
#pragma unroll
    for (int mt = 0; mt < 4; ++mt) {
#pragma unroll
        for (int nt = 0; nt < 4; ++nt) {
            int col = n0 + wc * 64 + nt * 16 + ln;
            int gate = col >> 9, r9 = col & 511;
            int slice = r9 >> 4, jj = r9 & 15;
            float bb = bias[col];
#pragma unroll
            for (int r = 0; r < 4; ++r) {
                int row = m0 + wr * 64 + mt * 16 + q * 4 + r;   // C/D: col=lane&15, row=quad*4+reg
                int t = row & 1023, bglob = row >> 10;
                int g = bglob >> 4, bloc = bglob & 15;
                size_t idx = ((((size_t)t * 4 + g) * 32 + slice) * 16 + bloc) * 64
                             + gate * 16 + jj;
                xpr[idx] = f2bf(acc[mt][nt][r] + bb);
            }
        }
    }
}

// ---------------------------------------------------------------------------
// Kernel 4: persistent LSTM recurrence — flagless data-as-flag, coalesced.
// 4 groups x 32 j-slices = 128 blocks, 1/CU. h stored fp32 with step tag in
// the low 2 mantissa bits: bits = (f32(h) & ~3) | ((s>>1)&3). Decode is free
// (3-ulp fp32 error vanishes in bf16 rounding). Consecutive writes to a slot
// differ by 1 mod 4; provable skew <= 1 step => stale always mismatches;
// 0xAA poison (tag 2) never collides with first-read tags (0,1).
// Consumers poll the data itself: 16 coalesced 8B agent loads per thread
// (c = tid + 256*i), retry only invalid chunks. Fire-and-forget stores.
// ---------------------------------------------------------------------------
__global__ __launch_bounds__(256, 1) void lstm_rec(
    const unsigned short* __restrict__ WhTg, // [2048][512] bf16 (pre-transposed Wh)
    const unsigned short* __restrict__ xpr,  // permuted x_proj (see gemm_xp)
    unsigned* __restrict__ hfp,              // [2][64][512] fp32 h, tag in low bits
    float* __restrict__ hmean)               // [64][512] fp32
{
    __shared__ __align__(16) unsigned short WhT[64 * 520];   // [col][k], pad 520
    __shared__ __align__(16) unsigned short hl[16 * 520];    // [b][k], pad 520
    __shared__ float gbuf[4][16][17];                        // [gate][b][j], pad 17

    const int tid = threadIdx.x;
    const int bid = blockIdx.x;
    const int g     = bid >> 5;        // batch group 0..3
    const int slice = bid & 31;        // j-slice 0..31
    const int j0    = slice * 16;
    const int bg    = g * 16;
    const int wv = tid >> 6, lane = tid & 63, ln = lane & 15, q = lane >> 4;

    // one-time: stage this block's 64 Wh columns (gate*16+j) from WhTg, coalesced
    for (int ch = tid; ch < 64 * 64; ch += 256) {            // 16B chunks
        int c = ch >> 6, off = (ch & 63) * 8;
        int gc = (c >> 4) * 512 + j0 + (c & 15);
        *(uint4*)&WhT[c * 520 + off] = *(const uint4*)&WhTg[(size_t)gc * 512 + off];
    }

    const int b = tid >> 4;            // local batch row 0..15
    const int j = tid & 15;            // local j
    const int rowoff = (bg + b) * 512;

    // h(0) = 0: zero the staged-h LDS (each thread zeros its stage chunks' area)
    {
        ull* hl8 = (ull*)hl;
#pragma unroll
        for (int i = 0; i < 16; ++i) {
            int c = tid + (i << 8);                          // ull chunk 0..4095
            int row = c >> 8, pair = c & 255;                // 256 ull per row
            hl8[(row * 1040 + pair * 8) >> 3] = 0ull;        // byte addr /8
        }
    }

    float c_st = 0.f, hsum = 0.f;
    const unsigned short* xblk0 = xpr + ((size_t)g * 32 + slice) * 1024 + b * 64 + j;
    unsigned short xc0 = xblk0[0], xc1 = xblk0[16], xc2 = xblk0[32], xc3 = xblk0[48];
    unsigned short xn0 = xc0, xn1 = xc1, xn2 = xc2, xn3 = xc3;

    for (int t = 0; t < T_; ++t) {
        // issue xp(t+1) prefetch FIRST: latency hides under the poll below
        if (t + 1 < T_) {
            const unsigned short* xr = xblk0 + (size_t)(t + 1) * 131072;  // 4*32*1024
            xn0 = xr[0]; xn1 = xr[16]; xn2 = xr[32]; xn3 = xr[48];
        }
        if (t > 0) {
            // poll h(t): coalesced 8B agent loads, per-dword tag check
            const ull* src = (const ull*)(hfp + (size_t)(t & 1) * 32768 + bg * 512);
            const unsigned want = (unsigned)((t >> 1) & 3);
            ull v[16];
#pragma unroll
            for (int i = 0; i < 16; ++i)
                v[i] = __hip_atomic_load(src + tid + (i << 8),
                                         __ATOMIC_RELAXED, __HIP_MEMORY_SCOPE_AGENT);
            while (true) {
                unsigned bad = 0u;
#pragma unroll
                for (int i = 0; i < 16; ++i) {
                    unsigned lo = (unsigned)v[i], hi = (unsigned)(v[i] >> 32);
                    bad |= ((((lo & 3u) ^ want) | ((hi & 3u) ^ want)) != 0u) ? (1u << i) : 0u;
                }
                if (!bad) break;
#pragma unroll
                for (int i = 0; i < 16; ++i)
                    if (bad & (1u << i))
                        v[i] = __hip_atomic_load(src + tid + (i << 8),
                                                 __ATOMIC_RELAXED, __HIP_MEMORY_SCOPE_AGENT);
            }
            // decode: fp32 (tag bits negligible) -> bf16 pair -> LDS (2-way free)
#pragma unroll
            for (int i = 0; i < 16; ++i) {
                int c = tid + (i << 8);
                int row = c >> 8, pair = c & 255;
                unsigned u = (unsigned)f2bf(__uint_as_float((unsigned)v[i]))
                           | ((unsigned)f2bf(__uint_as_float((unsigned)(v[i] >> 32))) << 16);
                *(unsigned*)((char*)hl + row * 1040 + pair * 4) = u;
            }
        }
        __syncthreads();                                     // sync1

        // wave wv computes gate wv: 16(batch) x 16(j), K=512
        f32x4 acc = (f32x4){0.f, 0.f, 0.f, 0.f};
#pragma unroll
        for (int kk = 0; kk < 16; ++kk) {
            short8 av = *(const short8*)&hl[ln * 520 + kk * 32 + q * 8];
            short8 bv = *(const short8*)&WhT[(wv * 16 + ln) * 520 + kk * 32 + q * 8];
            acc = __builtin_amdgcn_mfma_f32_16x16x32_bf16(av, bv, acc, 0, 0, 0);
        }
#pragma unroll
        for (int r = 0; r < 4; ++r)
            gbuf[wv][q * 4 + r][ln] = acc[r];                // C/D: col=lane&15, row=quad*4+reg
        __syncthreads();                                     // sync2

        // elementwise: thread (b, j)
        float ai  = gbuf[0][b][j] + bf2f((unsigned)xc0);
        float aj  = gbuf[1][b][j] + bf2f((unsigned)xc1);
        float af_ = gbuf[2][b][j] + bf2f((unsigned)xc2);
        float ao  = gbuf[3][b][j] + bf2f((unsigned)xc3);
        float si = sigm(ai), tj = tanhfast(aj);
        float sf = sigm(af_ + 1.0f), so = sigm(ao);
        c_st = c_st * sf + si * tj;
        float h = tanhfast(c_st) * so;
        hsum += h;
        xc0 = xn0; xc1 = xn1; xc2 = xn2; xc3 = xn3;

        // fire-and-forget tagged store of h(t+1); no drain, no flag
        unsigned hb = (__float_as_uint(h) & ~3u) | (unsigned)(((t + 1) >> 1) & 3);
        __hip_atomic_store(hfp + (size_t)((t + 1) & 1) * 32768 + rowoff + j0 + j,
                           hb, __ATOMIC_RELAXED, __HIP_MEMORY_SCOPE_AGENT);
    }
    hmean[(size_t)rowoff + j0 + j] = hsum * (1.f / 1024.f);
}

// ---------------------------------------------------------------------------
// Kernel 5: preds = sigmoid(hmean @ W_dense + b_dense), one wave per batch row
// ---------------------------------------------------------------------------
__global__ void dense_out(const float* __restrict__ hmean, const float* __restrict__ Wd,
                          const float* __restrict__ bd, float* __restrict__ out) {
    int bb = blockIdx.x;
    int lane = threadIdx.x;
    float p = 0.f;
    for (int e = lane; e < H_; e += 64) p += hmean[(size_t)bb * H_ + e] * Wd[e];
#pragma unroll
    for (int off = 32; off; off >>= 1) p += __shfl_down(p, off);
    if (lane == 0) out[bb] = 1.f / (1.f + __expf(-(p + bd[0])));
}

// ---------------------------------------------------------------------------
extern "C" void kernel_launch(void* const* d_in, const int* in_sizes, int n_in,
                              void* d_out, int out_size, void* d_ws, size_t ws_size,
                              hipStream_t stream) {
    const float* essays  = (const float*)d_in[0];
    const float* W_lstm  = (const float*)d_in[1];
    const float* b_lstm  = (const float*)d_in[2];
    const float* W_dense = (const float*)d_in[3];
    const float* b_dense = (const float*)d_in[4];
    float* out = (float*)d_out;

    char* ws = (char*)d_ws;
    unsigned short* xp   = (unsigned short*)(ws);                   // 256 MB (permuted)
    unsigned short* Ab   = (unsigned short*)(ws + 268435456ull);    // 40 MB (dead after gemm_xp)
    unsigned short* Bt   = (unsigned short*)(ws + 310378496ull);    // 1.25 MB
    unsigned short* WhTg = (unsigned short*)(ws + 311689216ull);    // 2 MB
    // hfp/hm overlap the Ab region (Ab dead once gemm_xp completes)
    unsigned*       hfp  = (unsigned*)(ws + 268435456ull);          // 256 KB
    float*          hm   = (float*)(ws + 268435456ull + 262144ull); // 128 KB

    hipLaunchKernelGGL(cvt_essays, dim3(81920), dim3(256), 0, stream, essays, Ab);
    hipLaunchKernelGGL(cvt_misc,   dim3(2560),  dim3(256), 0, stream, W_lstm, Bt);
    hipLaunchKernelGGL(cvt_wh,     dim3(4096),  dim3(256), 0, stream, W_lstm, WhTg);
    hipLaunchKernelGGL(gemm_xp,    dim3(8192),  dim3(256), 0, stream, Ab, Bt, b_lstm, xp);
    hipLaunchKernelGGL(lstm_rec,   dim3(128),   dim3(256), 0, stream, WhTg, xp, hfp, hm);
    hipLaunchKernelGGL(dense_out,  dim3(64),    dim3(64),  0, stream, hm, W_dense, b_dense, out);
}